// Round 2
// baseline (624.217 us; speedup 1.0000x reference)
//
#include <hip/hip_runtime.h>
#include <math.h>

#define NB 8
#define IC 256
#define CC 64
#define HH 128
#define WW 128
#define NN (HH*WW)      // 16384
#define NKW 32
#define NKC 32

// ---------------- workspace layout (floats) ----------------
static constexpr size_t SZ_INP  = (size_t)NB * CC * NN;          // 8,388,608
static constexpr size_t OFF_INP = 0;
static constexpr size_t OFF_S   = OFF_INP + SZ_INP;
static constexpr size_t OFF_PW  = OFF_S + SZ_INP;
static constexpr size_t SZ_PW   = (size_t)NB * NKW * 16384;
static constexpr size_t OFF_PC  = OFF_PW + SZ_PW;
static constexpr size_t SZ_PC   = (size_t)NB * NKC * 4096;
static constexpr size_t OFF_TW  = OFF_PC + SZ_PC;
static constexpr size_t OFF_TC  = OFF_TW + (size_t)NB * 16384;
static constexpr size_t OFF_WT  = OFF_TC + (size_t)NB * 4096;    // w_in_t [256 i][64 o]
static constexpr size_t OFF_WOT = OFF_WT + 16384;                // w_out_t [64 c][256 o]
// total ~22.22M floats = 88.9 MB

// ---------------- tiny transpose of both weight matrices ----------------
__global__ __launch_bounds__(256) void k_wt(
    const float* __restrict__ w_in, const float* __restrict__ w_out,
    float* __restrict__ w_in_t, float* __restrict__ w_out_t)
{
    const int idx = blockIdx.x * 256 + threadIdx.x;   // 0..32767
    if (idx < 16384) {
        const int o = idx & 63, i = idx >> 6;         // w_in_t[i][o] = w_in[o][i]
        w_in_t[idx] = w_in[o * IC + i];
    } else {
        const int j = idx - 16384;
        const int o = j & 255, c = j >> 8;            // w_out_t[c][o] = w_out[o][c]
        w_out_t[j] = w_out[o * CC + c];
    }
}

// ---------------- inconv: inp[b,o,n] = sum_i w_in[o,i]*x[b,i,n] + b_in[o] ----------------
// grid (NN/64, NB), block 256 = 64 n-lanes x 4 o-groups (16 o each, scalar weights)
__global__ __launch_bounds__(256) void k_inconv(
    const float* __restrict__ x, const float* __restrict__ wt,
    const float* __restrict__ b_in, float* __restrict__ inp)
{
    __shared__ float xs[64 * 65];   // [i][n], padded
    const int b  = blockIdx.y;
    const int n0 = blockIdx.x * 64;
    const int t  = threadIdx.x;
    const int tx = t & 63;
    const int ty = __builtin_amdgcn_readfirstlane(t >> 6);  // wave-uniform 0..3
    const int o0 = ty * 16;

    float acc[16];
#pragma unroll
    for (int j = 0; j < 16; j++) acc[j] = 0.f;

    const int sr = t >> 2, sq = (t & 3) * 16;
    for (int i0 = 0; i0 < IC; i0 += 64) {
        __syncthreads();
        {
            const float* src = x + ((size_t)b * IC + i0 + sr) * NN + n0 + sq;
            float* dst = xs + sr * 65 + sq;
#pragma unroll
            for (int k = 0; k < 4; k++)
                *(float4*)(dst + 4 * k) = *(const float4*)(src + 4 * k);
        }
        __syncthreads();
#pragma unroll 4
        for (int i = 0; i < 64; i++) {
            const float xv = xs[i * 65 + tx];
            const float* wr = wt + (size_t)(i0 + i) * 64 + o0;   // uniform -> s_load
#pragma unroll
            for (int j = 0; j < 16; j++) acc[j] += xv * wr[j];
        }
    }
    float* op = inp + ((size_t)b * CC + o0) * NN + n0 + tx;
#pragma unroll
    for (int j = 0; j < 16; j++) op[(size_t)j * NN] = acc[j] + b_in[o0 + j];
}

// ---------------- gram W partials (unchanged) ----------------
__global__ __launch_bounds__(256) void k_gramW(const float* __restrict__ inp, float* __restrict__ pW)
{
    __shared__ float xs[8 * 128];
    const int b = blockIdx.y, kc = blockIdx.x;
    const int t = threadIdx.x, tx = t & 15, ty = t >> 4;
    const float* Xb = inp + (size_t)b * CC * NN;
    const int k0 = kc * ((CC * HH) / NKW);

    float acc[8][8];
#pragma unroll
    for (int i = 0; i < 8; i++)
#pragma unroll
        for (int j = 0; j < 8; j++) acc[i][j] = 0.f;

    for (int kk = k0; kk < k0 + 256; kk += 8) {
        __syncthreads();
        for (int idx = t; idx < 1024; idx += 256)
            xs[idx] = Xb[((size_t)kk + (idx >> 7)) * WW + (idx & 127)];
        __syncthreads();
#pragma unroll
        for (int k = 0; k < 8; k++) {
            const float* row = xs + k * 128;
            float4 t0 = *(const float4*)(row + ty * 8);
            float4 t1 = *(const float4*)(row + ty * 8 + 4);
            float4 u0 = *(const float4*)(row + tx * 8);
            float4 u1 = *(const float4*)(row + tx * 8 + 4);
            float av[8] = {t0.x, t0.y, t0.z, t0.w, t1.x, t1.y, t1.z, t1.w};
            float bv[8] = {u0.x, u0.y, u0.z, u0.w, u1.x, u1.y, u1.z, u1.w};
#pragma unroll
            for (int i = 0; i < 8; i++)
#pragma unroll
                for (int j = 0; j < 8; j++) acc[i][j] += av[i] * bv[j];
        }
    }
    float* dst = pW + ((size_t)b * NKW + kc) * 16384;
#pragma unroll
    for (int i = 0; i < 8; i++)
#pragma unroll
        for (int j = 0; j < 8; j += 4) {
            float4 v = make_float4(acc[i][j], acc[i][j + 1], acc[i][j + 2], acc[i][j + 3]);
            *(float4*)(dst + (ty * 8 + i) * 128 + tx * 8 + j) = v;
        }
}

__global__ __launch_bounds__(256) void k_redW(const float* __restrict__ pW, float* __restrict__ Tw)
{
    const int b = blockIdx.y;
    const int idx = blockIdx.x * 256 + threadIdx.x;
    const float* p = pW + (size_t)b * NKW * 16384 + idx;
    float acc = 0.f;
#pragma unroll
    for (int k = 0; k < NKW; k++) acc += p[(size_t)k * 16384];
    Tw[(size_t)b * 16384 + idx] = acc;
}

__global__ __launch_bounds__(128) void k_softW(float* __restrict__ Tw)
{
    const int b = blockIdx.x, v = threadIdx.x;
    float* S = Tw + (size_t)b * 16384;
    float m = -3.4e38f;
    for (int w = 0; w < 128; w++) m = fmaxf(m, S[w * 128 + v]);
    float sum = 0.f;
    for (int w = 0; w < 128; w++) { float e = __expf(S[w * 128 + v] - m); sum += e; S[w * 128 + v] = e; }
    const float inv = 1.f / sum;
    for (int w = 0; w < 128; w++) S[w * 128 + v] *= inv;
}

// ---------------- gram C partials (unchanged) ----------------
__global__ __launch_bounds__(256) void k_gramC(const float* __restrict__ inp, float* __restrict__ pC)
{
    __shared__ float xs[64 * 33];
    const int b = blockIdx.y, nc = blockIdx.x;
    const int t = threadIdx.x, tx = t & 15, ty = t >> 4;
    const float* ip = inp + (size_t)b * CC * NN;
    const int n0 = nc * (NN / NKC);

    float acc[4][4];
#pragma unroll
    for (int i = 0; i < 4; i++)
#pragma unroll
        for (int j = 0; j < 4; j++) acc[i][j] = 0.f;

    const int scc = t >> 2, sq = t & 3;
    for (int nt = 0; nt < NN / NKC; nt += 32) {
        __syncthreads();
        {
            const float* src = ip + (size_t)scc * NN + n0 + nt + sq * 8;
            float* dst = xs + scc * 33 + sq * 8;
#pragma unroll
            for (int k = 0; k < 8; k++) dst[k] = src[k];
        }
        __syncthreads();
#pragma unroll 4
        for (int nn = 0; nn < 32; nn++) {
            float a0 = xs[(ty * 4 + 0) * 33 + nn];
            float a1 = xs[(ty * 4 + 1) * 33 + nn];
            float a2 = xs[(ty * 4 + 2) * 33 + nn];
            float a3 = xs[(ty * 4 + 3) * 33 + nn];
            float e0 = xs[(tx * 4 + 0) * 33 + nn];
            float e1 = xs[(tx * 4 + 1) * 33 + nn];
            float e2 = xs[(tx * 4 + 2) * 33 + nn];
            float e3 = xs[(tx * 4 + 3) * 33 + nn];
            acc[0][0] += a0 * e0; acc[0][1] += a0 * e1; acc[0][2] += a0 * e2; acc[0][3] += a0 * e3;
            acc[1][0] += a1 * e0; acc[1][1] += a1 * e1; acc[1][2] += a1 * e2; acc[1][3] += a1 * e3;
            acc[2][0] += a2 * e0; acc[2][1] += a2 * e1; acc[2][2] += a2 * e2; acc[2][3] += a2 * e3;
            acc[3][0] += a3 * e0; acc[3][1] += a3 * e1; acc[3][2] += a3 * e2; acc[3][3] += a3 * e3;
        }
    }
    float* dst = pC + ((size_t)b * NKC + nc) * 4096;
#pragma unroll
    for (int i = 0; i < 4; i++) {
        float4 v = make_float4(acc[i][0], acc[i][1], acc[i][2], acc[i][3]);
        *(float4*)(dst + (ty * 4 + i) * 64 + tx * 4) = v;
    }
}

__global__ __launch_bounds__(256) void k_redC(const float* __restrict__ pC, float* __restrict__ Tc)
{
    const int b = blockIdx.y;
    const int idx = blockIdx.x * 256 + threadIdx.x;
    const float* p = pC + (size_t)b * NKC * 4096 + idx;
    float acc = 0.f;
#pragma unroll
    for (int k = 0; k < NKC; k++) acc += p[(size_t)k * 4096];
    Tc[(size_t)b * 4096 + idx] = acc;
}

__global__ __launch_bounds__(64) void k_softC(float* __restrict__ Tc)
{
    const int b = blockIdx.x, d = threadIdx.x;
    float* S = Tc + (size_t)b * 4096;
    float m = -3.4e38f;
    for (int c = 0; c < 64; c++) m = fmaxf(m, S[c * 64 + d]);
    float sum = 0.f;
    for (int c = 0; c < 64; c++) { float e = __expf(S[c * 64 + d] - m); sum += e; S[c * 64 + d] = e; }
    const float inv = 1.f / sum;
    for (int c = 0; c < 64; c++) S[c * 64 + d] *= inv;
}

// ---------------- Co: s_flat[b][n*64+d] = detal * sum_c inp[b,c,n]*Tc[c,d] ----------------
// grid (NN/64, NB), block 256 = 64 n-lanes x 4 d-groups (16 d each, Tc scalar)
__global__ __launch_bounds__(256) void k_co(
    const float* __restrict__ inp, const float* __restrict__ Tc,
    const float* __restrict__ detal, float* __restrict__ s)
{
    __shared__ float xs[64 * 65];   // [c][n]
    const int b  = blockIdx.y;
    const int n0 = blockIdx.x * 64;
    const int t  = threadIdx.x;
    const int tx = t & 63;
    const int ty = __builtin_amdgcn_readfirstlane(t >> 6);
    const int d0 = ty * 16;

    {
        const int sr = t >> 2, sq = (t & 3) * 16;
        const float* src = inp + ((size_t)b * CC + sr) * NN + n0 + sq;
        float* dst = xs + sr * 65 + sq;
#pragma unroll
        for (int k = 0; k < 4; k++)
            *(float4*)(dst + 4 * k) = *(const float4*)(src + 4 * k);
    }
    __syncthreads();

    float acc[16];
#pragma unroll
    for (int j = 0; j < 16; j++) acc[j] = 0.f;

    const float* tb = Tc + (size_t)b * 4096 + d0;
#pragma unroll 4
    for (int c = 0; c < 64; c++) {
        const float xv = xs[c * 65 + tx];
        const float* tr = tb + c * 64;     // uniform -> s_load
#pragma unroll
        for (int j = 0; j < 16; j++) acc[j] += xv * tr[j];
    }
    const float sc = detal[0];
    float* sp = s + (size_t)b * CC * NN + (size_t)(n0 + tx) * 64 + d0;
#pragma unroll
    for (int j = 0; j < 16; j += 4) {
        float4 v = make_float4(acc[j] * sc, acc[j + 1] * sc, acc[j + 2] * sc, acc[j + 3] * sc);
        *(float4*)(sp + j) = v;
    }
}

// ---------------- Wo (==Ho): s[b,c,h,v] += 2*detal * sum_w inp[b,c,h,w]*Tw[w,v] ----------------
// grid (CC, 4 h-chunks, NB), block 128 = v-lanes; A rows via scalar loads, acc[32] h
__global__ __launch_bounds__(128) void k_wo(
    const float* __restrict__ inp, const float* __restrict__ Tw,
    const float* __restrict__ detal, float* __restrict__ s)
{
    const int b = blockIdx.z, c = blockIdx.x, h0 = blockIdx.y * 32;
    const int v = threadIdx.x;
    const float* A = inp + ((size_t)b * CC + c) * NN + (size_t)h0 * WW;   // [32 h][128 w]
    const float* T = Tw + (size_t)b * 16384;

    float acc[32];
#pragma unroll
    for (int h = 0; h < 32; h++) acc[h] = 0.f;

#pragma unroll 2
    for (int w = 0; w < 128; w++) {
        const float tv = T[(size_t)w * 128 + v];   // coalesced per-lane
#pragma unroll
        for (int h = 0; h < 32; h++) acc[h] += A[(size_t)h * 128 + w] * tv;  // uniform -> s_load
    }
    const float sc2 = 2.0f * detal[0];
    float* sp = s + ((size_t)b * CC + c) * NN + (size_t)h0 * WW + v;
#pragma unroll
    for (int h = 0; h < 32; h++) sp[(size_t)h * 128] += sc2 * acc[h];
}

// ---------------- outconv: out[b,o,n] = sum_c w_out[o,c]*s[b,c,n] + b_out[o] + x[b,o,n] ----------------
// grid (NN/64, NB), block 256 = 64 n-lanes x 4 o-groups (64 o each, scalar weights)
__global__ __launch_bounds__(256) void k_outconv(
    const float* __restrict__ s, const float* __restrict__ wot,
    const float* __restrict__ b_out, const float* __restrict__ x,
    float* __restrict__ outp)
{
    __shared__ float ss[64 * 65];   // [c][n]
    const int b  = blockIdx.y;
    const int n0 = blockIdx.x * 64;
    const int t  = threadIdx.x;
    const int tx = t & 63;
    const int ty = __builtin_amdgcn_readfirstlane(t >> 6);
    const int o0 = ty * 64;

    {
        const int sr = t >> 2, sq = (t & 3) * 16;
        const float* src = s + ((size_t)b * CC + sr) * NN + n0 + sq;
        float* dst = ss + sr * 65 + sq;
#pragma unroll
        for (int k = 0; k < 4; k++)
            *(float4*)(dst + 4 * k) = *(const float4*)(src + 4 * k);
    }
    __syncthreads();

    float acc[64];
#pragma unroll
    for (int j = 0; j < 64; j++) acc[j] = 0.f;

#pragma unroll 2
    for (int c = 0; c < 64; c++) {
        const float sv = ss[c * 65 + tx];
        const float* wr = wot + (size_t)c * IC + o0;   // uniform -> s_load
#pragma unroll
        for (int j = 0; j < 64; j++) acc[j] += sv * wr[j];
    }

    const float* xb = x + ((size_t)b * IC + o0) * NN + n0 + tx;
    float* ob = outp + ((size_t)b * IC + o0) * NN + n0 + tx;
#pragma unroll
    for (int j = 0; j < 64; j++)
        ob[(size_t)j * NN] = acc[j] + b_out[o0 + j] + xb[(size_t)j * NN];
}

extern "C" void kernel_launch(void* const* d_in, const int* in_sizes, int n_in,
                              void* d_out, int out_size, void* d_ws, size_t ws_size,
                              hipStream_t stream)
{
    const float* x     = (const float*)d_in[0];
    const float* w_in  = (const float*)d_in[1];
    const float* b_in  = (const float*)d_in[2];
    const float* w_out = (const float*)d_in[3];
    const float* b_out = (const float*)d_in[4];
    const float* detal = (const float*)d_in[5];
    float* out = (float*)d_out;

    float* ws   = (float*)d_ws;
    float* inp  = ws + OFF_INP;
    float* s    = ws + OFF_S;
    float* pW   = ws + OFF_PW;
    float* pC   = ws + OFF_PC;
    float* Tw   = ws + OFF_TW;
    float* Tc   = ws + OFF_TC;
    float* wt   = ws + OFF_WT;
    float* wot  = ws + OFF_WOT;

    k_wt     <<<dim3(128),            256, 0, stream>>>(w_in, w_out, wt, wot);
    k_inconv <<<dim3(NN / 64, NB),    256, 0, stream>>>(x, wt, b_in, inp);
    k_gramW  <<<dim3(NKW, NB),        256, 0, stream>>>(inp, pW);
    k_redW   <<<dim3(64, NB),         256, 0, stream>>>(pW, Tw);
    k_softW  <<<dim3(NB),             128, 0, stream>>>(Tw);
    k_gramC  <<<dim3(NKC, NB),        256, 0, stream>>>(inp, pC);
    k_redC   <<<dim3(16, NB),         256, 0, stream>>>(pC, Tc);
    k_softC  <<<dim3(NB),              64, 0, stream>>>(Tc);
    k_co     <<<dim3(NN / 64, NB),    256, 0, stream>>>(inp, Tc, detal, s);
    k_wo     <<<dim3(CC, 4, NB),      128, 0, stream>>>(inp, Tw, detal, s);
    k_outconv<<<dim3(NN / 64, NB),    256, 0, stream>>>(s, wot, b_out, x, out);
}

// Round 3
// 512.096 us; speedup vs baseline: 1.2189x; 1.2189x over previous
//
#include <hip/hip_runtime.h>
#include <math.h>

#define NB 8
#define IC 256
#define CC 64
#define HH 128
#define WW 128
#define NN (HH*WW)      // 16384
#define NKW 32
#define NKC 32

// ---------------- workspace layout (floats) ----------------
static constexpr size_t SZ_INP  = (size_t)NB * CC * NN;          // 8,388,608
static constexpr size_t OFF_INP = 0;
static constexpr size_t OFF_S   = OFF_INP + SZ_INP;
static constexpr size_t OFF_PW  = OFF_S + SZ_INP;
static constexpr size_t SZ_PW   = (size_t)NB * NKW * 16384;
static constexpr size_t OFF_PC  = OFF_PW + SZ_PW;
static constexpr size_t SZ_PC   = (size_t)NB * NKC * 4096;
static constexpr size_t OFF_TW  = OFF_PC + SZ_PC;
static constexpr size_t OFF_TC  = OFF_TW + (size_t)NB * 16384;
static constexpr size_t OFF_WT  = OFF_TC + (size_t)NB * 4096;    // w_in_t [256 i][64 o]
static constexpr size_t OFF_WOT = OFF_WT + 16384;                // w_out_t [64 c][256 o]

// ---------------- tiny transpose of both weight matrices ----------------
__global__ __launch_bounds__(256) void k_wt(
    const float* __restrict__ w_in, const float* __restrict__ w_out,
    float* __restrict__ w_in_t, float* __restrict__ w_out_t)
{
    const int idx = blockIdx.x * 256 + threadIdx.x;   // 0..32767
    if (idx < 16384) {
        const int o = idx & 63, i = idx >> 6;         // w_in_t[i][o] = w_in[o][i]
        w_in_t[idx] = w_in[o * IC + i];
    } else {
        const int j = idx - 16384;
        const int o = j & 255, c = j >> 8;            // w_out_t[c][o] = w_out[o][c]
        w_out_t[j] = w_out[o * CC + c];
    }
}

// ---------------- inconv: inp[b,o,n] = sum_i w_in[o,i]*x[b,i,n] + b_in[o] ----------------
// grid (NN/64, NB), block 256; 64o x 64n tile; both operands in LDS, 4x4 reg tile
__global__ __launch_bounds__(256) void k_inconv(
    const float* __restrict__ x, const float* __restrict__ wt,
    const float* __restrict__ b_in, float* __restrict__ inp)
{
    __shared__ float wl[64 * 64];   // [i_local][o], 16 KB
    __shared__ float xs[64 * 64];   // [i_local][n], 16 KB
    const int b  = blockIdx.y;
    const int n0 = blockIdx.x * 64;
    const int t  = threadIdx.x;
    const int o4 = (t >> 4) * 4;
    const int n4 = (t & 15) * 4;

    float acc[4][4];
#pragma unroll
    for (int i = 0; i < 4; i++)
#pragma unroll
        for (int j = 0; j < 4; j++) acc[i][j] = 0.f;

    const int sr = t >> 2, sq = (t & 3) * 16;
    for (int i0 = 0; i0 < IC; i0 += 64) {
        __syncthreads();
        {
            const float* src = x + ((size_t)b * IC + i0 + sr) * NN + n0 + sq;
            float* dst = xs + sr * 64 + sq;
#pragma unroll
            for (int k = 0; k < 4; k++)
                *(float4*)(dst + 4 * k) = *(const float4*)(src + 4 * k);
            const float* wsrc = wt + (size_t)(i0 + sr) * 64 + sq;
            float* wdst = wl + sr * 64 + sq;
#pragma unroll
            for (int k = 0; k < 4; k++)
                *(float4*)(wdst + 4 * k) = *(const float4*)(wsrc + 4 * k);
        }
        __syncthreads();
#pragma unroll 8
        for (int i = 0; i < 64; i++) {
            float4 a4 = *(const float4*)(wl + i * 64 + o4);
            float4 x4 = *(const float4*)(xs + i * 64 + n4);
            acc[0][0] += a4.x * x4.x; acc[0][1] += a4.x * x4.y; acc[0][2] += a4.x * x4.z; acc[0][3] += a4.x * x4.w;
            acc[1][0] += a4.y * x4.x; acc[1][1] += a4.y * x4.y; acc[1][2] += a4.y * x4.z; acc[1][3] += a4.y * x4.w;
            acc[2][0] += a4.z * x4.x; acc[2][1] += a4.z * x4.y; acc[2][2] += a4.z * x4.z; acc[2][3] += a4.z * x4.w;
            acc[3][0] += a4.w * x4.x; acc[3][1] += a4.w * x4.y; acc[3][2] += a4.w * x4.z; acc[3][3] += a4.w * x4.w;
        }
    }
#pragma unroll
    for (int o = 0; o < 4; o++) {
        const int oo = o4 + o;
        const float bo = b_in[oo];
        float4 v = make_float4(acc[o][0] + bo, acc[o][1] + bo, acc[o][2] + bo, acc[o][3] + bo);
        *(float4*)(inp + ((size_t)b * CC + oo) * NN + n0 + n4) = v;
    }
}

// ---------------- gram W partials (unchanged) ----------------
__global__ __launch_bounds__(256) void k_gramW(const float* __restrict__ inp, float* __restrict__ pW)
{
    __shared__ float xs[8 * 128];
    const int b = blockIdx.y, kc = blockIdx.x;
    const int t = threadIdx.x, tx = t & 15, ty = t >> 4;
    const float* Xb = inp + (size_t)b * CC * NN;
    const int k0 = kc * ((CC * HH) / NKW);

    float acc[8][8];
#pragma unroll
    for (int i = 0; i < 8; i++)
#pragma unroll
        for (int j = 0; j < 8; j++) acc[i][j] = 0.f;

    for (int kk = k0; kk < k0 + 256; kk += 8) {
        __syncthreads();
        for (int idx = t; idx < 1024; idx += 256)
            xs[idx] = Xb[((size_t)kk + (idx >> 7)) * WW + (idx & 127)];
        __syncthreads();
#pragma unroll
        for (int k = 0; k < 8; k++) {
            const float* row = xs + k * 128;
            float4 t0 = *(const float4*)(row + ty * 8);
            float4 t1 = *(const float4*)(row + ty * 8 + 4);
            float4 u0 = *(const float4*)(row + tx * 8);
            float4 u1 = *(const float4*)(row + tx * 8 + 4);
            float av[8] = {t0.x, t0.y, t0.z, t0.w, t1.x, t1.y, t1.z, t1.w};
            float bv[8] = {u0.x, u0.y, u0.z, u0.w, u1.x, u1.y, u1.z, u1.w};
#pragma unroll
            for (int i = 0; i < 8; i++)
#pragma unroll
                for (int j = 0; j < 8; j++) acc[i][j] += av[i] * bv[j];
        }
    }
    float* dst = pW + ((size_t)b * NKW + kc) * 16384;
#pragma unroll
    for (int i = 0; i < 8; i++)
#pragma unroll
        for (int j = 0; j < 8; j += 4) {
            float4 v = make_float4(acc[i][j], acc[i][j + 1], acc[i][j + 2], acc[i][j + 3]);
            *(float4*)(dst + (ty * 8 + i) * 128 + tx * 8 + j) = v;
        }
}

__global__ __launch_bounds__(256) void k_redW(const float* __restrict__ pW, float* __restrict__ Tw)
{
    const int b = blockIdx.y;
    const int idx = blockIdx.x * 256 + threadIdx.x;
    const float* p = pW + (size_t)b * NKW * 16384 + idx;
    float acc = 0.f;
#pragma unroll
    for (int k = 0; k < NKW; k++) acc += p[(size_t)k * 16384];
    Tw[(size_t)b * 16384 + idx] = acc;
}

__global__ __launch_bounds__(128) void k_softW(float* __restrict__ Tw)
{
    const int b = blockIdx.x, v = threadIdx.x;
    float* S = Tw + (size_t)b * 16384;
    float m = -3.4e38f;
    for (int w = 0; w < 128; w++) m = fmaxf(m, S[w * 128 + v]);
    float sum = 0.f;
    for (int w = 0; w < 128; w++) { float e = __expf(S[w * 128 + v] - m); sum += e; S[w * 128 + v] = e; }
    const float inv = 1.f / sum;
    for (int w = 0; w < 128; w++) S[w * 128 + v] *= inv;
}

// ---------------- gram C partials (unchanged) ----------------
__global__ __launch_bounds__(256) void k_gramC(const float* __restrict__ inp, float* __restrict__ pC)
{
    __shared__ float xs[64 * 33];
    const int b = blockIdx.y, nc = blockIdx.x;
    const int t = threadIdx.x, tx = t & 15, ty = t >> 4;
    const float* ip = inp + (size_t)b * CC * NN;
    const int n0 = nc * (NN / NKC);

    float acc[4][4];
#pragma unroll
    for (int i = 0; i < 4; i++)
#pragma unroll
        for (int j = 0; j < 4; j++) acc[i][j] = 0.f;

    const int scc = t >> 2, sq = t & 3;
    for (int nt = 0; nt < NN / NKC; nt += 32) {
        __syncthreads();
        {
            const float* src = ip + (size_t)scc * NN + n0 + nt + sq * 8;
            float* dst = xs + scc * 33 + sq * 8;
#pragma unroll
            for (int k = 0; k < 8; k++) dst[k] = src[k];
        }
        __syncthreads();
#pragma unroll 4
        for (int nn = 0; nn < 32; nn++) {
            float a0 = xs[(ty * 4 + 0) * 33 + nn];
            float a1 = xs[(ty * 4 + 1) * 33 + nn];
            float a2 = xs[(ty * 4 + 2) * 33 + nn];
            float a3 = xs[(ty * 4 + 3) * 33 + nn];
            float e0 = xs[(tx * 4 + 0) * 33 + nn];
            float e1 = xs[(tx * 4 + 1) * 33 + nn];
            float e2 = xs[(tx * 4 + 2) * 33 + nn];
            float e3 = xs[(tx * 4 + 3) * 33 + nn];
            acc[0][0] += a0 * e0; acc[0][1] += a0 * e1; acc[0][2] += a0 * e2; acc[0][3] += a0 * e3;
            acc[1][0] += a1 * e0; acc[1][1] += a1 * e1; acc[1][2] += a1 * e2; acc[1][3] += a1 * e3;
            acc[2][0] += a2 * e0; acc[2][1] += a2 * e1; acc[2][2] += a2 * e2; acc[2][3] += a2 * e3;
            acc[3][0] += a3 * e0; acc[3][1] += a3 * e1; acc[3][2] += a3 * e2; acc[3][3] += a3 * e3;
        }
    }
    float* dst = pC + ((size_t)b * NKC + nc) * 4096;
#pragma unroll
    for (int i = 0; i < 4; i++) {
        float4 v = make_float4(acc[i][0], acc[i][1], acc[i][2], acc[i][3]);
        *(float4*)(dst + (ty * 4 + i) * 64 + tx * 4) = v;
    }
}

__global__ __launch_bounds__(256) void k_redC(const float* __restrict__ pC, float* __restrict__ Tc)
{
    const int b = blockIdx.y;
    const int idx = blockIdx.x * 256 + threadIdx.x;
    const float* p = pC + (size_t)b * NKC * 4096 + idx;
    float acc = 0.f;
#pragma unroll
    for (int k = 0; k < NKC; k++) acc += p[(size_t)k * 4096];
    Tc[(size_t)b * 4096 + idx] = acc;
}

__global__ __launch_bounds__(64) void k_softC(float* __restrict__ Tc)
{
    const int b = blockIdx.x, d = threadIdx.x;
    float* S = Tc + (size_t)b * 4096;
    float m = -3.4e38f;
    for (int c = 0; c < 64; c++) m = fmaxf(m, S[c * 64 + d]);
    float sum = 0.f;
    for (int c = 0; c < 64; c++) { float e = __expf(S[c * 64 + d] - m); sum += e; S[c * 64 + d] = e; }
    const float inv = 1.f / sum;
    for (int c = 0; c < 64; c++) S[c * 64 + d] *= inv;
}

// ---------------- Co: s_flat[b][n*64+d] = detal * sum_c inp[b,c,n]*Tc[c,d] ----------------
// grid (NN/64, NB), block 256; 64d x 64n tile; Tc + inp tiles in LDS, 4x4 reg tile
// lanes vary d (contiguous stores), groups vary n
__global__ __launch_bounds__(256) void k_co(
    const float* __restrict__ inp, const float* __restrict__ Tc,
    const float* __restrict__ detal, float* __restrict__ s)
{
    __shared__ float tc[64 * 64];   // [c][d], 16 KB
    __shared__ float xs[64 * 64];   // [c][n], 16 KB
    const int b  = blockIdx.y;
    const int n0 = blockIdx.x * 64;
    const int t  = threadIdx.x;
    const int d4 = (t & 15) * 4;
    const int ng = (t >> 4) * 4;

    {
        const int sr = t >> 2, sq = (t & 3) * 16;
        const float* src = inp + ((size_t)b * CC + sr) * NN + n0 + sq;
        float* dst = xs + sr * 64 + sq;
#pragma unroll
        for (int k = 0; k < 4; k++)
            *(float4*)(dst + 4 * k) = *(const float4*)(src + 4 * k);
        const float* tsrc = Tc + (size_t)b * 4096 + sr * 64 + sq;
        float* tdst = tc + sr * 64 + sq;
#pragma unroll
        for (int k = 0; k < 4; k++)
            *(float4*)(tdst + 4 * k) = *(const float4*)(tsrc + 4 * k);
    }
    __syncthreads();

    float acc[4][4];   // [n][d]
#pragma unroll
    for (int i = 0; i < 4; i++)
#pragma unroll
        for (int j = 0; j < 4; j++) acc[i][j] = 0.f;

#pragma unroll 8
    for (int c = 0; c < 64; c++) {
        float4 t4 = *(const float4*)(tc + c * 64 + d4);
        float4 x4 = *(const float4*)(xs + c * 64 + ng);
        acc[0][0] += x4.x * t4.x; acc[0][1] += x4.x * t4.y; acc[0][2] += x4.x * t4.z; acc[0][3] += x4.x * t4.w;
        acc[1][0] += x4.y * t4.x; acc[1][1] += x4.y * t4.y; acc[1][2] += x4.y * t4.z; acc[1][3] += x4.y * t4.w;
        acc[2][0] += x4.z * t4.x; acc[2][1] += x4.z * t4.y; acc[2][2] += x4.z * t4.z; acc[2][3] += x4.z * t4.w;
        acc[3][0] += x4.w * t4.x; acc[3][1] += x4.w * t4.y; acc[3][2] += x4.w * t4.z; acc[3][3] += x4.w * t4.w;
    }
    const float sc = detal[0];
    float* sb = s + (size_t)b * CC * NN;
#pragma unroll
    for (int i = 0; i < 4; i++) {
        const int n = n0 + ng + i;
        float4 v = make_float4(acc[i][0] * sc, acc[i][1] * sc, acc[i][2] * sc, acc[i][3] * sc);
        *(float4*)(sb + (size_t)n * 64 + d4) = v;
    }
}

// ---------------- Wo (==Ho): s[b,c,h,v] += 2*detal * sum_w inp[b,c,h,w]*Tw[w,v] ----------------
// grid (CC, NB), block 256; Tw (64 KB) + 32-row stage (16 KB) in LDS — round-1 design
__global__ __launch_bounds__(256) void k_wo(
    const float* __restrict__ inp, const float* __restrict__ Tw,
    const float* __restrict__ detal, float* __restrict__ s)
{
    __shared__ float tw[128 * 128];   // 64 KB [w][v]
    __shared__ float rs[32 * 128];    // 16 KB [r][w]
    const int b = blockIdx.y, c = blockIdx.x;
    const int t = threadIdx.x;
    const int v4 = (t & 31) * 4;
    const int rg = t >> 5;

    const float* twg = Tw + (size_t)b * 16384;
    for (int idx = t * 4; idx < 16384; idx += 1024)
        *(float4*)(tw + idx) = *(const float4*)(twg + idx);

    const float* ip = inp + ((size_t)b * CC + c) * NN;
    float* sp = s + ((size_t)b * CC + c) * NN;
    const float sc2 = 2.0f * detal[0];
    const int sr = t >> 3, sq = (t & 7) * 16;

    for (int h0 = 0; h0 < HH; h0 += 32) {
        __syncthreads();
        {
            const float* src = ip + (size_t)(h0 + sr) * WW + sq;
            float* dst = rs + sr * 128 + sq;
#pragma unroll
            for (int k = 0; k < 4; k++)
                *(float4*)(dst + 4 * k) = *(const float4*)(src + 4 * k);
        }
        __syncthreads();

        float acc[4][4];
#pragma unroll
        for (int i = 0; i < 4; i++)
#pragma unroll
            for (int j = 0; j < 4; j++) acc[i][j] = 0.f;

#pragma unroll 4
        for (int w = 0; w < 128; w++) {
            float4 tv = *(const float4*)(tw + w * 128 + v4);
#pragma unroll
            for (int i = 0; i < 4; i++) {
                float a = rs[(rg * 4 + i) * 128 + w];
                acc[i][0] += a * tv.x; acc[i][1] += a * tv.y;
                acc[i][2] += a * tv.z; acc[i][3] += a * tv.w;
            }
        }
#pragma unroll
        for (int i = 0; i < 4; i++) {
            const int h = h0 + rg * 4 + i;
            float* p = sp + (size_t)h * WW + v4;
            float4 cur = *(const float4*)p;
            cur.x += sc2 * acc[i][0]; cur.y += sc2 * acc[i][1];
            cur.z += sc2 * acc[i][2]; cur.w += sc2 * acc[i][3];
            *(float4*)p = cur;
        }
    }
}

// ---------------- outconv: out[b,o,n] = sum_c w_out[o,c]*s[b,c,n] + b_out[o] + x[b,o,n] ----------------
// grid (NN/64, 4 o-chunks, NB), block 256; 64o x 64n tile, both operands in LDS
__global__ __launch_bounds__(256) void k_outconv(
    const float* __restrict__ s, const float* __restrict__ wot,
    const float* __restrict__ b_out, const float* __restrict__ x,
    float* __restrict__ outp)
{
    __shared__ float wl[64 * 64];   // [c][o_local], 16 KB
    __shared__ float ss[64 * 64];   // [c][n], 16 KB
    const int b  = blockIdx.z;
    const int o0 = blockIdx.y * 64;
    const int n0 = blockIdx.x * 64;
    const int t  = threadIdx.x;
    const int o4 = (t >> 4) * 4;
    const int n4 = (t & 15) * 4;

    {
        const int sr = t >> 2, sq = (t & 3) * 16;
        const float* src = s + ((size_t)b * CC + sr) * NN + n0 + sq;
        float* dst = ss + sr * 64 + sq;
#pragma unroll
        for (int k = 0; k < 4; k++)
            *(float4*)(dst + 4 * k) = *(const float4*)(src + 4 * k);
        const float* wsrc = wot + (size_t)sr * IC + o0 + sq;
        float* wdst = wl + sr * 64 + sq;
#pragma unroll
        for (int k = 0; k < 4; k++)
            *(float4*)(wdst + 4 * k) = *(const float4*)(wsrc + 4 * k);
    }
    __syncthreads();

    float acc[4][4];   // [o][n]
#pragma unroll
    for (int i = 0; i < 4; i++)
#pragma unroll
        for (int j = 0; j < 4; j++) acc[i][j] = 0.f;

#pragma unroll 8
    for (int c = 0; c < 64; c++) {
        float4 a4 = *(const float4*)(wl + c * 64 + o4);
        float4 s4 = *(const float4*)(ss + c * 64 + n4);
        acc[0][0] += a4.x * s4.x; acc[0][1] += a4.x * s4.y; acc[0][2] += a4.x * s4.z; acc[0][3] += a4.x * s4.w;
        acc[1][0] += a4.y * s4.x; acc[1][1] += a4.y * s4.y; acc[1][2] += a4.y * s4.z; acc[1][3] += a4.y * s4.w;
        acc[2][0] += a4.z * s4.x; acc[2][1] += a4.z * s4.y; acc[2][2] += a4.z * s4.z; acc[2][3] += a4.z * s4.w;
        acc[3][0] += a4.w * s4.x; acc[3][1] += a4.w * s4.y; acc[3][2] += a4.w * s4.z; acc[3][3] += a4.w * s4.w;
    }

#pragma unroll
    for (int o = 0; o < 4; o++) {
        const int oo = o0 + o4 + o;
        const float bo = b_out[oo];
        const float4 xv = *(const float4*)(x + ((size_t)b * IC + oo) * NN + n0 + n4);
        float4 v = make_float4(acc[o][0] + bo + xv.x, acc[o][1] + bo + xv.y,
                               acc[o][2] + bo + xv.z, acc[o][3] + bo + xv.w);
        *(float4*)(outp + ((size_t)b * IC + oo) * NN + n0 + n4) = v;
    }
}

extern "C" void kernel_launch(void* const* d_in, const int* in_sizes, int n_in,
                              void* d_out, int out_size, void* d_ws, size_t ws_size,
                              hipStream_t stream)
{
    const float* x     = (const float*)d_in[0];
    const float* w_in  = (const float*)d_in[1];
    const float* b_in  = (const float*)d_in[2];
    const float* w_out = (const float*)d_in[3];
    const float* b_out = (const float*)d_in[4];
    const float* detal = (const float*)d_in[5];
    float* out = (float*)d_out;

    float* ws   = (float*)d_ws;
    float* inp  = ws + OFF_INP;
    float* s    = ws + OFF_S;
    float* pW   = ws + OFF_PW;
    float* pC   = ws + OFF_PC;
    float* Tw   = ws + OFF_TW;
    float* Tc   = ws + OFF_TC;
    float* wt   = ws + OFF_WT;
    float* wot  = ws + OFF_WOT;

    k_wt     <<<dim3(128),             256, 0, stream>>>(w_in, w_out, wt, wot);
    k_inconv <<<dim3(NN / 64, NB),     256, 0, stream>>>(x, wt, b_in, inp);
    k_gramW  <<<dim3(NKW, NB),         256, 0, stream>>>(inp, pW);
    k_redW   <<<dim3(64, NB),          256, 0, stream>>>(pW, Tw);
    k_softW  <<<dim3(NB),              128, 0, stream>>>(Tw);
    k_gramC  <<<dim3(NKC, NB),         256, 0, stream>>>(inp, pC);
    k_redC   <<<dim3(16, NB),          256, 0, stream>>>(pC, Tc);
    k_softC  <<<dim3(NB),               64, 0, stream>>>(Tc);
    k_co     <<<dim3(NN / 64, NB),     256, 0, stream>>>(inp, Tc, detal, s);
    k_wo     <<<dim3(CC, NB),          256, 0, stream>>>(inp, Tw, detal, s);
    k_outconv<<<dim3(NN / 64, 4, NB),  256, 0, stream>>>(s, wot, b_out, x, out);
}